// Round 8
// baseline (296.831 us; speedup 1.0000x reference)
//
#include <hip/hip_runtime.h>
#include <hip/hip_fp8.h>
#include <math.h>

#define M_ROWS 16384   // B*S
#define E_DIM 768
#define FFN_DIM 3072
#define NQ 8

// h stored as fp8*16, W2^T as fp8*32; GEMM3 epilogue multiplies by 1/512.
#define HSCALE 16.0f
#define WSCALE 32.0f
#define INV_SCALE (1.0f / (16.0f * 32.0f))

typedef __bf16 bf16x8 __attribute__((ext_vector_type(8)));
typedef float f32x4 __attribute__((ext_vector_type(4)));
typedef unsigned short ushortx8 __attribute__((ext_vector_type(8)));
typedef unsigned short ushortx4 __attribute__((ext_vector_type(4)));
typedef int intx4 __attribute__((ext_vector_type(4)));
typedef int intx8 __attribute__((ext_vector_type(8)));
typedef unsigned short ushort;
typedef unsigned char uchar;

union F8frag { intx4 h[2]; intx8 v; };

static __device__ __forceinline__ ushort f2bf(float f) {
    unsigned u = __float_as_uint(f);
    unsigned r = (u + 0x7FFFu + ((u >> 16) & 1u)) >> 16;
    return (ushort)r;
}
static __device__ __forceinline__ float bf2f(ushort u) {
    return __uint_as_float(((unsigned)u) << 16);
}
static __device__ __forceinline__ uchar f2fp8(float f) {
    return (uchar)__hip_cvt_float_to_fp8(f, __HIP_SATFINITE, __HIP_E4M3);
}
static __device__ __forceinline__ bf16x8 as_bf16x8(ushortx8 v) {
    union { ushortx8 u; bf16x8 b; } x; x.u = v; return x.b;
}

// Tiled fp8 layout for w2T8: value (n, k) lives at
//   base + ((n>>4)*(K/16) + (k>>4))*256 + (n&15)*16 + (k&15)

// ---------------------------------------------------------------------------
// Kernel 1: transpose fp32 (R x C) -> bf16 (C x R)   [for Wc]
// ---------------------------------------------------------------------------
__global__ __launch_bounds__(256) void k_transpose_bf(const float* __restrict__ in,
                                                      ushort* __restrict__ out,
                                                      int R, int C) {
    __shared__ float tile[32][33];
    int c0 = blockIdx.x * 32, r0 = blockIdx.y * 32;
    int tx = threadIdx.x & 31, ty = threadIdx.x >> 5;
#pragma unroll
    for (int i = 0; i < 32; i += 8)
        tile[ty + i][tx] = in[(long)(r0 + ty + i) * C + c0 + tx];
    __syncthreads();
#pragma unroll
    for (int i = 0; i < 32; i += 8)
        out[(long)(c0 + ty + i) * R + r0 + tx] = f2bf(tile[tx][ty + i]);
}

// ---------------------------------------------------------------------------
// Kernel 2: W2 [R=K][C=N] f32 -> w2T8 fp8*WSCALE in TILED [N][K] layout.
// ---------------------------------------------------------------------------
__global__ __launch_bounds__(256) void k_transpose_fp8t(const float* __restrict__ in,
                                                        uchar* __restrict__ out,
                                                        int R, int C) {
    __shared__ float tile[32][33];
    int c0 = blockIdx.x * 32, r0 = blockIdx.y * 32;
    int tx = threadIdx.x & 31, ty = threadIdx.x >> 5;
#pragma unroll
    for (int i = 0; i < 32; i += 8)
        tile[ty + i][tx] = in[(long)(r0 + ty + i) * C + c0 + tx];
    __syncthreads();
    int k = r0 + tx;
#pragma unroll
    for (int i = 0; i < 32; i += 8) {
        int n = c0 + ty + i;
        long addr = ((long)(n >> 4) * (R >> 4) + (k >> 4)) * 256 + (n & 15) * 16 + (k & 15);
        out[addr] = f2fp8(tile[tx][ty + i] * WSCALE);
    }
}

// ---------------------------------------------------------------------------
// Kernel 2b: W1 [NQ][FFN] f32 -> w1t [FFN][NQ] bf16 (16B row per n).
// ---------------------------------------------------------------------------
__global__ __launch_bounds__(256) void k_w1t(const float* __restrict__ W1,
                                             ushort* __restrict__ w1t) {
    int n = blockIdx.x * 256 + threadIdx.x;
    ushortx8 o;
#pragma unroll
    for (int j = 0; j < NQ; ++j) o[j] = f2bf(W1[j * FFN_DIM + n]);
    *(ushortx8*)(w1t + (long)n * NQ) = o;
}

// ---------------------------------------------------------------------------
// Kernel 3: GEMM1 with fused A = bf16(cos(x + rx)) staging.  (R6-verified)
// C[M,N] = cos(X+rx)[M,K] * Bt[N,K]^T + bias[N], bf16 out.
// ---------------------------------------------------------------------------
__global__ __launch_bounds__(256, 2)
void k_gemm1(const float* __restrict__ X, const ushort* __restrict__ Bt,
             const float* __restrict__ rx, const float* __restrict__ bias,
             ushort* __restrict__ C, int M, int N, int K) {
    __shared__ __align__(16) ushort lsA[128 * 64];
    __shared__ __align__(16) ushort lsB[128 * 64];
    const int tid = threadIdx.x;
    const int lane = tid & 63;
    const int wave = tid >> 6;
    const int wm = wave & 1, wn = wave >> 1;
    const long m0 = (long)blockIdx.x * 128;
    const long n0 = (long)blockIdx.y * 128;

    const int srow = tid >> 3;
    const int fcol = (tid & 7) * 8;
    const int swc = (tid & 7) ^ (srow & 7);
    const float* gX = X + (m0 + srow) * (long)K + fcol;
    const ushort* gB = Bt + (n0 + srow) * (long)K + fcol;
    ushort* wA = lsA + srow * 64 + swc * 8;
    ushort* wB = lsB + srow * 64 + swc * 8;

    float rxv[8];
#pragma unroll
    for (int j = 0; j < 8; ++j) rxv[j] = rx[fcol + j];

    f32x4 acc[4][4] = {};
    const int rbase = lane & 15;
    const int khalf = lane >> 4;
    const int rswz = lane & 7;

    for (int kt = 0; kt < K; kt += 64) {
        float xv[4][8];
        ushortx8 bv[4];
#pragma unroll
        for (int i = 0; i < 4; ++i) {
            float4 lo = *(const float4*)(gX + kt + (long)(32 * i) * K);
            float4 hi = *(const float4*)(gX + kt + (long)(32 * i) * K + 4);
            xv[i][0] = lo.x; xv[i][1] = lo.y; xv[i][2] = lo.z; xv[i][3] = lo.w;
            xv[i][4] = hi.x; xv[i][5] = hi.y; xv[i][6] = hi.z; xv[i][7] = hi.w;
            bv[i] = *(const ushortx8*)(gB + kt + (long)(32 * i) * K);
        }
        if (kt) __syncthreads();
#pragma unroll
        for (int i = 0; i < 4; ++i) {
            ushortx8 o;
#pragma unroll
            for (int j = 0; j < 8; ++j) o[j] = f2bf(__cosf(xv[i][j] + rxv[j]));
            *(ushortx8*)(wA + i * 2048) = o;
            *(ushortx8*)(wB + i * 2048) = bv[i];
        }
        __syncthreads();
#pragma unroll
        for (int kk = 0; kk < 64; kk += 32) {
            const int ko = (((kk >> 3) + khalf) ^ rswz) * 8;
            bf16x8 af[4], bfr[4];
#pragma unroll
            for (int t = 0; t < 4; ++t) {
                af[t]  = as_bf16x8(*(const ushortx8*)&lsA[(wm * 64 + t * 16 + rbase) * 64 + ko]);
                bfr[t] = as_bf16x8(*(const ushortx8*)&lsB[(wn * 64 + t * 16 + rbase) * 64 + ko]);
            }
#pragma unroll
            for (int tm = 0; tm < 4; ++tm)
#pragma unroll
                for (int tn = 0; tn < 4; ++tn)
                    acc[tm][tn] = __builtin_amdgcn_mfma_f32_16x16x32_bf16(af[tm], bfr[tn], acc[tm][tn], 0, 0, 0);
        }
    }

    const int cr = (lane >> 4) * 4;
    const int cc = lane & 15;
#pragma unroll
    for (int tm = 0; tm < 4; ++tm)
#pragma unroll
        for (int tn = 0; tn < 4; ++tn) {
            long col = n0 + wn * 64 + tn * 16 + cc;
            float bb = bias[col];
#pragma unroll
            for (int j = 0; j < 4; ++j) {
                long row = m0 + wm * 64 + tm * 16 + cr + j;
                C[row * N + col] = f2bf(acc[tm][tn][j] + bb);
            }
        }
}

// ---------------------------------------------------------------------------
// Kernel 4: FUSED FFN.  ffn[m,n] = (relu(q[m]@W1+b1)*16 @ w2T8)/512 + b2.
// Block = 64 m-rows x N=768 x K=3072, 512 threads (8 waves: wm=wv&1,
// wn=wv>>1).  K processed in 4 chunks of 768:
//   producer: h-chunk 64x768 fp8 -> LDS (exact k_ffn1 math: mfma(w1f, qf),
//     lane = (m=lid, k=half*4+reg), store uchar4 at tiled byte lid*16+half*4)
//   consumer: mfma_scale 16x16x128; A-frag = 2 contiguous 16B LDS chunks
//     (layout [mt][kt16][m&15][k&15]); B-frag read from L2-resident tiled
//     w2T8 directly (2 x global 16B).  No h8 HBM round-trip (saves 100 MB).
// Accumulation k-order identical to the split kernels -> same absmax.
// ---------------------------------------------------------------------------
#define KC 768          // k-chunk (48 kt16 tiles, 6 k128 tiles)
__global__ __launch_bounds__(512, 2)
void k_ffn_fused(const float* __restrict__ q, const ushort* __restrict__ w1t,
                 const float* __restrict__ b1, const uchar* __restrict__ Bt,
                 const float* __restrict__ b2, ushort* __restrict__ C) {
    __shared__ __align__(16) uchar lsH[4 * 48 * 256];   // 48 KB: [mt][kt16][16][16]
    const int tid = threadIdx.x;
    const int lane = tid & 63;
    const int wv = tid >> 6;          // 0..7
    const int wm = wv & 1;            // m-half (32 rows)
    const int wn = wv >> 1;           // 0..3 (192 n-cols)
    const long m0 = (long)blockIdx.x * 64;
    const int lid = lane & 15;
    const int half = lane >> 4;       // 0..3
    const int K = FFN_DIM;

    // q-frags: qf[mt] lanes 0-15 = q[m0 + mt*16 + lid][0..7] bf16, else 0
    bf16x8 qf[4] = {};
    if (lane < 16) {
#pragma unroll
        for (int mt = 0; mt < 4; ++mt) {
            const float* qp = q + (m0 + mt * 16 + lid) * NQ;
            float4 lo = *(const float4*)qp;
            float4 hi = *(const float4*)(qp + 4);
            ushortx8 u;
            u[0] = f2bf(lo.x); u[1] = f2bf(lo.y); u[2] = f2bf(lo.z); u[3] = f2bf(lo.w);
            u[4] = f2bf(hi.x); u[5] = f2bf(hi.y); u[6] = f2bf(hi.z); u[7] = f2bf(hi.w);
            qf[mt] = as_bf16x8(u);
        }
    }

    f32x4 acc[2][12] = {};

    for (int kc = 0; kc < K; kc += KC) {
        if (kc) __syncthreads();      // consumers done with previous h-chunk
        // ---- producer: this wave covers kt16 = wv*6 .. wv*6+5 ----
#pragma unroll
        for (int s = 0; s < 6; ++s) {
            const int kt16 = wv * 6 + s;            // chunk-relative 0..47
            const int kabs = kc + kt16 * 16;
            bf16x8 wf = {};
            if (lane < 16) wf = as_bf16x8(*(const ushortx8*)(w1t + (long)(kabs + lid) * NQ));
            float4 bb = *(const float4*)(b1 + kabs + half * 4);
#pragma unroll
            for (int mt = 0; mt < 4; ++mt) {
                f32x4 p = {};
                p = __builtin_amdgcn_mfma_f32_16x16x32_bf16(wf, qf[mt], p, 0, 0, 0);
                uchar4 o;
                o.x = f2fp8(fmaxf(p[0] + bb.x, 0.f) * HSCALE);
                o.y = f2fp8(fmaxf(p[1] + bb.y, 0.f) * HSCALE);
                o.z = f2fp8(fmaxf(p[2] + bb.z, 0.f) * HSCALE);
                o.w = f2fp8(fmaxf(p[3] + bb.w, 0.f) * HSCALE);
                *(uchar4*)&lsH[(mt * 48 + kt16) * 256 + lid * 16 + half * 4] = o;
            }
        }
        __syncthreads();              // h-chunk ready
        // ---- consumer: 6 k128-tiles over this chunk ----
#pragma unroll 1
        for (int t = 0; t < 6; ++t) {
            F8frag af[2];
#pragma unroll
            for (int fm = 0; fm < 2; ++fm) {
                const int mt = wm * 2 + fm;
                const int crel = t * 8 + half * 2;
                af[fm].h[0] = *(const intx4*)&lsH[(mt * 48 + crel) * 256 + lid * 16];
                af[fm].h[1] = *(const intx4*)&lsH[(mt * 48 + crel + 1) * 256 + lid * 16];
            }
            const int kabs = kc + t * 128;
#pragma unroll
            for (int fn = 0; fn < 12; ++fn) {
                const int ntile = wn * 12 + fn;
                const uchar* bp = Bt + ((long)ntile * (K >> 4) + (kabs >> 4) + half * 2) * 256 + lid * 16;
                F8frag bf;
                bf.h[0] = *(const intx4*)bp;
                bf.h[1] = *(const intx4*)(bp + 256);
                acc[0][fn] = __builtin_amdgcn_mfma_scale_f32_16x16x128_f8f6f4(
                    af[0].v, bf.v, acc[0][fn], 0, 0, 0, 127, 0, 127);
                acc[1][fn] = __builtin_amdgcn_mfma_scale_f32_16x16x128_f8f6f4(
                    af[1].v, bf.v, acc[1][fn], 0, 0, 0, 127, 0, 127);
            }
        }
    }

    // ---- epilogue (same mapping as verified gemm_fp8) ----
    const int cr = half * 4;
    const int cc = lid;
#pragma unroll
    for (int fm = 0; fm < 2; ++fm)
#pragma unroll
        for (int fn = 0; fn < 12; ++fn) {
            long col = wn * 192 + fn * 16 + cc;
            float bb = b2[col];
#pragma unroll
            for (int j = 0; j < 4; ++j) {
                long row = m0 + wm * 32 + fm * 16 + cr + j;
                C[row * E_DIM + col] = f2bf(acc[fm][fn][j] * INV_SCALE + bb);
            }
        }
}
#undef KC

// ---------------------------------------------------------------------------
// Kernel 5: LN1: x1(bf16) = LN(x_f32 + attn_bf16); q = cos(x1[:, :8])*cos(ry)
// ---------------------------------------------------------------------------
__global__ __launch_bounds__(256) void k_ln1(const float* __restrict__ x,
                                             const ushort* __restrict__ y,
                                             const float* __restrict__ g,
                                             const float* __restrict__ b,
                                             ushort* __restrict__ out,
                                             float* __restrict__ qout,
                                             const float* __restrict__ ry) {
    const int lane = threadIdx.x & 63;
    const int wave = threadIdx.x >> 6;
    const long row = (long)blockIdx.x * 4 + wave;
    const float* xr = x + row * E_DIM;
    const ushort* yr = y + row * E_DIM;
    float4 v[3];
    float s = 0.f, ss = 0.f;
#pragma unroll
    for (int i = 0; i < 3; ++i) {
        int c = lane * 4 + i * 256;
        float4 a = *(const float4*)(xr + c);
        ushortx4 d4 = *(const ushortx4*)(yr + c);
        v[i].x = a.x + bf2f(d4[0]); v[i].y = a.y + bf2f(d4[1]);
        v[i].z = a.z + bf2f(d4[2]); v[i].w = a.w + bf2f(d4[3]);
        s  += v[i].x + v[i].y + v[i].z + v[i].w;
        ss += v[i].x * v[i].x + v[i].y * v[i].y + v[i].z * v[i].z + v[i].w * v[i].w;
    }
#pragma unroll
    for (int o = 1; o < 64; o <<= 1) {
        s  += __shfl_xor(s, o);
        ss += __shfl_xor(ss, o);
    }
    const float mu = s * (1.f / E_DIM);
    const float rstd = rsqrtf(ss * (1.f / E_DIM) - mu * mu + 1e-5f);
#pragma unroll
    for (int i = 0; i < 3; ++i) {
        int c = lane * 4 + i * 256;
        float4 gg = *(const float4*)(g + c);
        float4 bb = *(const float4*)(b + c);
        float4 o;
        o.x = (v[i].x - mu) * rstd * gg.x + bb.x;
        o.y = (v[i].y - mu) * rstd * gg.y + bb.y;
        o.z = (v[i].z - mu) * rstd * gg.z + bb.z;
        o.w = (v[i].w - mu) * rstd * gg.w + bb.w;
        ushortx4 o4;
        o4[0] = f2bf(o.x); o4[1] = f2bf(o.y); o4[2] = f2bf(o.z); o4[3] = f2bf(o.w);
        *(ushortx4*)(out + row * E_DIM + c) = o4;
        if (i == 0 && lane < 2) {
            float4 r4 = *(const float4*)(ry + lane * 4);
            float* qo = qout + row * NQ + lane * 4;
            qo[0] = __cosf(o.x) * __cosf(r4.x);
            qo[1] = __cosf(o.y) * __cosf(r4.y);
            qo[2] = __cosf(o.z) * __cosf(r4.z);
            qo[3] = __cosf(o.w) * __cosf(r4.w);
        }
    }
}

// ---------------------------------------------------------------------------
// Kernel 6: LN2: out(f32) = LN(x1_bf16 + ffn_bf16)
// ---------------------------------------------------------------------------
__global__ __launch_bounds__(256) void k_ln2(const ushort* __restrict__ x,
                                             const ushort* __restrict__ y,
                                             const float* __restrict__ g,
                                             const float* __restrict__ b,
                                             float* __restrict__ out) {
    const int lane = threadIdx.x & 63;
    const int wave = threadIdx.x >> 6;
    const long row = (long)blockIdx.x * 4 + wave;
    const ushort* xr = x + row * E_DIM;
    const ushort* yr = y + row * E_DIM;
    float4 v[3];
    float s = 0.f, ss = 0.f;
#pragma unroll
    for (int i = 0; i < 3; ++i) {
        int c = lane * 4 + i * 256;
        ushortx4 a4 = *(const ushortx4*)(xr + c);
        ushortx4 d4 = *(const ushortx4*)(yr + c);
        v[i].x = bf2f(a4[0]) + bf2f(d4[0]); v[i].y = bf2f(a4[1]) + bf2f(d4[1]);
        v[i].z = bf2f(a4[2]) + bf2f(d4[2]); v[i].w = bf2f(a4[3]) + bf2f(d4[3]);
        s  += v[i].x + v[i].y + v[i].z + v[i].w;
        ss += v[i].x * v[i].x + v[i].y * v[i].y + v[i].z * v[i].z + v[i].w * v[i].w;
    }
#pragma unroll
    for (int o = 1; o < 64; o <<= 1) {
        s  += __shfl_xor(s, o);
        ss += __shfl_xor(ss, o);
    }
    const float mu = s * (1.f / E_DIM);
    const float rstd = rsqrtf(ss * (1.f / E_DIM) - mu * mu + 1e-5f);
#pragma unroll
    for (int i = 0; i < 3; ++i) {
        int c = lane * 4 + i * 256;
        float4 gg = *(const float4*)(g + c);
        float4 bb = *(const float4*)(b + c);
        float4 o;
        o.x = (v[i].x - mu) * rstd * gg.x + bb.x;
        o.y = (v[i].y - mu) * rstd * gg.y + bb.y;
        o.z = (v[i].z - mu) * rstd * gg.z + bb.z;
        o.w = (v[i].w - mu) * rstd * gg.w + bb.w;
        *(float4*)(out + row * E_DIM + c) = o;
    }
}

// ---------------------------------------------------------------------------

extern "C" void kernel_launch(void* const* d_in, const int* in_sizes, int n_in,
                              void* d_out, int out_size, void* d_ws, size_t ws_size,
                              hipStream_t stream) {
    const float* x   = (const float*)d_in[0];
    const float* rx  = (const float*)d_in[1];
    const float* ry  = (const float*)d_in[2];
    const float* Wc  = (const float*)d_in[3];
    const float* bc  = (const float*)d_in[4];
    const float* W1  = (const float*)d_in[5];
    const float* b1  = (const float*)d_in[6];
    const float* W2  = (const float*)d_in[7];
    const float* b2  = (const float*)d_in[8];
    const float* g1  = (const float*)d_in[9];
    const float* be1 = (const float*)d_in[10];
    const float* g2  = (const float*)d_in[11];
    const float* be2 = (const float*)d_in[12];
    float* out = (float*)d_out;

    char* ws = (char*)d_ws;
    ushort* wcT  = (ushort*)ws;                 ws += (size_t)E_DIM * E_DIM * 2;      // 1.2 MB
    ushort* attn = (ushort*)ws;                 ws += (size_t)M_ROWS * E_DIM * 2;     // 25 MB (bf16, reused as ffn_out)
    ushort* x1   = (ushort*)ws;                 ws += (size_t)M_ROWS * E_DIM * 2;     // 25 MB (bf16)
    float*  q    = (float*)ws;                  ws += (size_t)M_ROWS * NQ * 4;        // 0.5 MB
    uchar*  w2T8 = (uchar*)ws;                  ws += (size_t)E_DIM * FFN_DIM;        // 2.4 MB (tiled)
    ushort* w1tb = (ushort*)ws;                 ws += (size_t)FFN_DIM * NQ * 2;       // 48 KB

    // 1. WcT = bf16(Wc^T);  W2T8 = fp8(W2^T * 32) tiled;  w1tb = bf16(W1^T)
    k_transpose_bf<<<dim3(E_DIM / 32, E_DIM / 32), 256, 0, stream>>>(Wc, wcT, E_DIM, E_DIM);
    k_transpose_fp8t<<<dim3(E_DIM / 32, FFN_DIM / 32), 256, 0, stream>>>(W2, w2T8, FFN_DIM, E_DIM);
    k_w1t<<<dim3(FFN_DIM / 256), 256, 0, stream>>>(W1, w1tb);
    // 2. attn(bf16) = cos(x+rx) @ Wc + bc   (cos fused into staging)
    k_gemm1<<<dim3(M_ROWS / 128, E_DIM / 128), 256, 0, stream>>>(x, wcT, rx, bc, attn, M_ROWS, E_DIM, E_DIM);
    // 3. x1(bf16) = LN(x + attn); q = cos(x1[:, :8]) * cos(ry)
    k_ln1<<<M_ROWS / 4, 256, 0, stream>>>(x, attn, g1, be1, x1, q, ry);
    // 4+5 fused. ffn(bf16) = (relu(q@W1+b1)*16 @ w2T8)/512 + b2  (reuse attn)
    k_ffn_fused<<<dim3(M_ROWS / 64), 512, 0, stream>>>(q, w1tb, b1, w2T8, b2, attn);
    // 6. out = LN(x1 + ffn)
    k_ln2<<<M_ROWS / 4, 256, 0, stream>>>(x1, attn, g2, be2, out);
}

// Round 9
// 276.520 us; speedup vs baseline: 1.0735x; 1.0735x over previous
//
#include <hip/hip_runtime.h>
#include <hip/hip_fp8.h>
#include <math.h>

#define M_ROWS 16384   // B*S
#define E_DIM 768
#define FFN_DIM 3072
#define NQ 8

// h stored as fp8*16, W2^T as fp8*32; GEMM3 epilogue multiplies by 1/512.
#define HSCALE 16.0f
#define WSCALE 32.0f
#define INV_SCALE (1.0f / (16.0f * 32.0f))

typedef __bf16 bf16x8 __attribute__((ext_vector_type(8)));
typedef float f32x4 __attribute__((ext_vector_type(4)));
typedef unsigned short ushortx8 __attribute__((ext_vector_type(8)));
typedef unsigned short ushortx4 __attribute__((ext_vector_type(4)));
typedef int intx4 __attribute__((ext_vector_type(4)));
typedef int intx8 __attribute__((ext_vector_type(8)));
typedef unsigned short ushort;
typedef unsigned char uchar;

union F8frag { intx4 h[2]; intx8 v; };

static __device__ __forceinline__ ushort f2bf(float f) {
    unsigned u = __float_as_uint(f);
    unsigned r = (u + 0x7FFFu + ((u >> 16) & 1u)) >> 16;
    return (ushort)r;
}
static __device__ __forceinline__ float bf2f(ushort u) {
    return __uint_as_float(((unsigned)u) << 16);
}
static __device__ __forceinline__ uchar f2fp8(float f) {
    return (uchar)__hip_cvt_float_to_fp8(f, __HIP_SATFINITE, __HIP_E4M3);
}
static __device__ __forceinline__ bf16x8 as_bf16x8(ushortx8 v) {
    union { ushortx8 u; bf16x8 b; } x; x.u = v; return x.b;
}

// Tiled fp8 layout for w2T8: value (n, k) lives at
//   base + ((n>>4)*(K/16) + (k>>4))*256 + (n&15)*16 + (k&15)

// ---------------------------------------------------------------------------
// Kernel 1: transpose fp32 (R x C) -> bf16 (C x R)   [for Wc]
// ---------------------------------------------------------------------------
__global__ __launch_bounds__(256) void k_transpose_bf(const float* __restrict__ in,
                                                      ushort* __restrict__ out,
                                                      int R, int C) {
    __shared__ float tile[32][33];
    int c0 = blockIdx.x * 32, r0 = blockIdx.y * 32;
    int tx = threadIdx.x & 31, ty = threadIdx.x >> 5;
#pragma unroll
    for (int i = 0; i < 32; i += 8)
        tile[ty + i][tx] = in[(long)(r0 + ty + i) * C + c0 + tx];
    __syncthreads();
#pragma unroll
    for (int i = 0; i < 32; i += 8)
        out[(long)(c0 + ty + i) * R + r0 + tx] = f2bf(tile[tx][ty + i]);
}

// ---------------------------------------------------------------------------
// Kernel 2: W2 [R=K][C=N] f32 -> w2T8 fp8*WSCALE in TILED [N][K] layout.
// ---------------------------------------------------------------------------
__global__ __launch_bounds__(256) void k_transpose_fp8t(const float* __restrict__ in,
                                                        uchar* __restrict__ out,
                                                        int R, int C) {
    __shared__ float tile[32][33];
    int c0 = blockIdx.x * 32, r0 = blockIdx.y * 32;
    int tx = threadIdx.x & 31, ty = threadIdx.x >> 5;
#pragma unroll
    for (int i = 0; i < 32; i += 8)
        tile[ty + i][tx] = in[(long)(r0 + ty + i) * C + c0 + tx];
    __syncthreads();
    int k = r0 + tx;
#pragma unroll
    for (int i = 0; i < 32; i += 8) {
        int n = c0 + ty + i;
        long addr = ((long)(n >> 4) * (R >> 4) + (k >> 4)) * 256 + (n & 15) * 16 + (k & 15);
        out[addr] = f2fp8(tile[tx][ty + i] * WSCALE);
    }
}

// ---------------------------------------------------------------------------
// Kernel 2b: W1 [NQ][FFN] f32 -> w1t [FFN][NQ] bf16 (16B row per n).
// ---------------------------------------------------------------------------
__global__ __launch_bounds__(256) void k_w1t(const float* __restrict__ W1,
                                             ushort* __restrict__ w1t) {
    int n = blockIdx.x * 256 + threadIdx.x;
    ushortx8 o;
#pragma unroll
    for (int j = 0; j < NQ; ++j) o[j] = f2bf(W1[j * FFN_DIM + n]);
    *(ushortx8*)(w1t + (long)n * NQ) = o;
}

// ---------------------------------------------------------------------------
// Kernel 3: GEMM1 with fused A = bf16(cos(x + rx)) staging.  (R6-verified)
// C[M,N] = cos(X+rx)[M,K] * Bt[N,K]^T + bias[N], bf16 out.
// ---------------------------------------------------------------------------
__global__ __launch_bounds__(256, 2)
void k_gemm1(const float* __restrict__ X, const ushort* __restrict__ Bt,
             const float* __restrict__ rx, const float* __restrict__ bias,
             ushort* __restrict__ C, int M, int N, int K) {
    __shared__ __align__(16) ushort lsA[128 * 64];
    __shared__ __align__(16) ushort lsB[128 * 64];
    const int tid = threadIdx.x;
    const int lane = tid & 63;
    const int wave = tid >> 6;
    const int wm = wave & 1, wn = wave >> 1;
    const long m0 = (long)blockIdx.x * 128;
    const long n0 = (long)blockIdx.y * 128;

    const int srow = tid >> 3;
    const int fcol = (tid & 7) * 8;
    const int swc = (tid & 7) ^ (srow & 7);
    const float* gX = X + (m0 + srow) * (long)K + fcol;
    const ushort* gB = Bt + (n0 + srow) * (long)K + fcol;
    ushort* wA = lsA + srow * 64 + swc * 8;
    ushort* wB = lsB + srow * 64 + swc * 8;

    float rxv[8];
#pragma unroll
    for (int j = 0; j < 8; ++j) rxv[j] = rx[fcol + j];

    f32x4 acc[4][4] = {};
    const int rbase = lane & 15;
    const int khalf = lane >> 4;
    const int rswz = lane & 7;

    for (int kt = 0; kt < K; kt += 64) {
        float xv[4][8];
        ushortx8 bv[4];
#pragma unroll
        for (int i = 0; i < 4; ++i) {
            float4 lo = *(const float4*)(gX + kt + (long)(32 * i) * K);
            float4 hi = *(const float4*)(gX + kt + (long)(32 * i) * K + 4);
            xv[i][0] = lo.x; xv[i][1] = lo.y; xv[i][2] = lo.z; xv[i][3] = lo.w;
            xv[i][4] = hi.x; xv[i][5] = hi.y; xv[i][6] = hi.z; xv[i][7] = hi.w;
            bv[i] = *(const ushortx8*)(gB + kt + (long)(32 * i) * K);
        }
        if (kt) __syncthreads();
#pragma unroll
        for (int i = 0; i < 4; ++i) {
            ushortx8 o;
#pragma unroll
            for (int j = 0; j < 8; ++j) o[j] = f2bf(__cosf(xv[i][j] + rxv[j]));
            *(ushortx8*)(wA + i * 2048) = o;
            *(ushortx8*)(wB + i * 2048) = bv[i];
        }
        __syncthreads();
#pragma unroll
        for (int kk = 0; kk < 64; kk += 32) {
            const int ko = (((kk >> 3) + khalf) ^ rswz) * 8;
            bf16x8 af[4], bfr[4];
#pragma unroll
            for (int t = 0; t < 4; ++t) {
                af[t]  = as_bf16x8(*(const ushortx8*)&lsA[(wm * 64 + t * 16 + rbase) * 64 + ko]);
                bfr[t] = as_bf16x8(*(const ushortx8*)&lsB[(wn * 64 + t * 16 + rbase) * 64 + ko]);
            }
#pragma unroll
            for (int tm = 0; tm < 4; ++tm)
#pragma unroll
                for (int tn = 0; tn < 4; ++tn)
                    acc[tm][tn] = __builtin_amdgcn_mfma_f32_16x16x32_bf16(af[tm], bfr[tn], acc[tm][tn], 0, 0, 0);
        }
    }

    const int cr = (lane >> 4) * 4;
    const int cc = lane & 15;
#pragma unroll
    for (int tm = 0; tm < 4; ++tm)
#pragma unroll
        for (int tn = 0; tn < 4; ++tn) {
            long col = n0 + wn * 64 + tn * 16 + cc;
            float bb = bias[col];
#pragma unroll
            for (int j = 0; j < 4; ++j) {
                long row = m0 + wm * 64 + tm * 16 + cr + j;
                C[row * N + col] = f2bf(acc[tm][tn][j] + bb);
            }
        }
}

// ---------------------------------------------------------------------------
// Kernel 4: FUSED FFN, re-tiled for occupancy (R8's math, new geometry).
// Block = 64 m x 192 n, 256 threads (4 waves; wave wv owns n-slice wv*48,
// so waves read DISJOINT B -> B L2-traffic invariant at (M/64)*N*K=604MB).
// Grid = (M/64) x (N/192) = 1024 blocks -> 4 blocks/CU, 16 waves/CU.
// K in 8 chunks of 384: producer fills LDS h-chunk [4 mt][24 kt16][256]
// (24 KB; exact R8 fragment math), consumer runs 3 k128 MX tiles.
// Producer work duplicated x4 across n-blocks (cheap: ~120 vs 310 cyc).
// Accumulation k-order identical to R8 -> same absmax.
// ---------------------------------------------------------------------------
#define KC 384
__global__ __launch_bounds__(256, 4)
void k_ffn_fused(const float* __restrict__ q, const ushort* __restrict__ w1t,
                 const float* __restrict__ b1, const uchar* __restrict__ Bt,
                 const float* __restrict__ b2, ushort* __restrict__ C) {
    __shared__ __align__(16) uchar lsH[4 * 24 * 256];   // 24 KB
    const int tid = threadIdx.x;
    const int lane = tid & 63;
    const int wv = tid >> 6;          // 0..3 = this wave's n-slice
    const long m0 = (long)blockIdx.x * 64;
    const int nq = blockIdx.y;        // n0 = nq*192
    const int lid = lane & 15;
    const int half = lane >> 4;       // 0..3
    const int K16 = FFN_DIM >> 4;     // 192

    // q-frags: qf[mt] lanes 0-15 = q[m0 + mt*16 + lid][0..7] bf16, else 0
    bf16x8 qf[4] = {};
    if (lane < 16) {
#pragma unroll
        for (int mt = 0; mt < 4; ++mt) {
            const float* qp = q + (m0 + mt * 16 + lid) * NQ;
            float4 lo = *(const float4*)qp;
            float4 hi = *(const float4*)(qp + 4);
            ushortx8 u;
            u[0] = f2bf(lo.x); u[1] = f2bf(lo.y); u[2] = f2bf(lo.z); u[3] = f2bf(lo.w);
            u[4] = f2bf(hi.x); u[5] = f2bf(hi.y); u[6] = f2bf(hi.z); u[7] = f2bf(hi.w);
            qf[mt] = as_bf16x8(u);
        }
    }

    f32x4 acc[4][3] = {};

    for (int c = 0; c < FFN_DIM / KC; ++c) {   // 8 chunks
        if (c) __syncthreads();       // consumers done with previous h-chunk
        // ---- producer: this wave covers kt16 = wv*6 .. wv*6+5 ----
#pragma unroll
        for (int s = 0; s < 6; ++s) {
            const int kt16 = wv * 6 + s;            // chunk-relative 0..23
            const int kabs = c * KC + kt16 * 16;
            bf16x8 wf = {};
            if (lane < 16) wf = as_bf16x8(*(const ushortx8*)(w1t + (long)(kabs + lid) * NQ));
            float4 bb = *(const float4*)(b1 + kabs + half * 4);
#pragma unroll
            for (int mt = 0; mt < 4; ++mt) {
                f32x4 p = {};
                p = __builtin_amdgcn_mfma_f32_16x16x32_bf16(wf, qf[mt], p, 0, 0, 0);
                uchar4 o;
                o.x = f2fp8(fmaxf(p[0] + bb.x, 0.f) * HSCALE);
                o.y = f2fp8(fmaxf(p[1] + bb.y, 0.f) * HSCALE);
                o.z = f2fp8(fmaxf(p[2] + bb.z, 0.f) * HSCALE);
                o.w = f2fp8(fmaxf(p[3] + bb.w, 0.f) * HSCALE);
                *(uchar4*)&lsH[(mt * 24 + kt16) * 256 + lid * 16 + half * 4] = o;
            }
        }
        __syncthreads();              // h-chunk ready
        // ---- consumer: 3 k128-tiles over this chunk ----
#pragma unroll 1
        for (int t = 0; t < 3; ++t) {
            F8frag af[4];
#pragma unroll
            for (int mt = 0; mt < 4; ++mt) {
                const int crel = t * 8 + half * 2;
                af[mt].h[0] = *(const intx4*)&lsH[(mt * 24 + crel) * 256 + lid * 16];
                af[mt].h[1] = *(const intx4*)&lsH[(mt * 24 + crel + 1) * 256 + lid * 16];
            }
            const int kidx16 = c * 24 + t * 8 + half * 2;
#pragma unroll
            for (int fn = 0; fn < 3; ++fn) {
                const int ntile = nq * 12 + wv * 3 + fn;
                const uchar* bp = Bt + ((long)ntile * K16 + kidx16) * 256 + lid * 16;
                F8frag bf;
                bf.h[0] = *(const intx4*)bp;
                bf.h[1] = *(const intx4*)(bp + 256);
#pragma unroll
                for (int mt = 0; mt < 4; ++mt)
                    acc[mt][fn] = __builtin_amdgcn_mfma_scale_f32_16x16x128_f8f6f4(
                        af[mt].v, bf.v, acc[mt][fn], 0, 0, 0, 127, 0, 127);
            }
        }
    }

    // ---- epilogue (verified gemm_fp8 mapping) ----
    const int cr = half * 4;
    const int cc = lid;
#pragma unroll
    for (int mt = 0; mt < 4; ++mt)
#pragma unroll
        for (int fn = 0; fn < 3; ++fn) {
            long col = (long)nq * 192 + wv * 48 + fn * 16 + cc;
            float bb = b2[col];
#pragma unroll
            for (int j = 0; j < 4; ++j) {
                long row = m0 + mt * 16 + cr + j;
                C[row * E_DIM + col] = f2bf(acc[mt][fn][j] * INV_SCALE + bb);
            }
        }
}
#undef KC

// ---------------------------------------------------------------------------
// Kernel 5: LN1: x1(bf16) = LN(x_f32 + attn_bf16); q = cos(x1[:, :8])*cos(ry)
// ---------------------------------------------------------------------------
__global__ __launch_bounds__(256) void k_ln1(const float* __restrict__ x,
                                             const ushort* __restrict__ y,
                                             const float* __restrict__ g,
                                             const float* __restrict__ b,
                                             ushort* __restrict__ out,
                                             float* __restrict__ qout,
                                             const float* __restrict__ ry) {
    const int lane = threadIdx.x & 63;
    const int wave = threadIdx.x >> 6;
    const long row = (long)blockIdx.x * 4 + wave;
    const float* xr = x + row * E_DIM;
    const ushort* yr = y + row * E_DIM;
    float4 v[3];
    float s = 0.f, ss = 0.f;
#pragma unroll
    for (int i = 0; i < 3; ++i) {
        int c = lane * 4 + i * 256;
        float4 a = *(const float4*)(xr + c);
        ushortx4 d4 = *(const ushortx4*)(yr + c);
        v[i].x = a.x + bf2f(d4[0]); v[i].y = a.y + bf2f(d4[1]);
        v[i].z = a.z + bf2f(d4[2]); v[i].w = a.w + bf2f(d4[3]);
        s  += v[i].x + v[i].y + v[i].z + v[i].w;
        ss += v[i].x * v[i].x + v[i].y * v[i].y + v[i].z * v[i].z + v[i].w * v[i].w;
    }
#pragma unroll
    for (int o = 1; o < 64; o <<= 1) {
        s  += __shfl_xor(s, o);
        ss += __shfl_xor(ss, o);
    }
    const float mu = s * (1.f / E_DIM);
    const float rstd = rsqrtf(ss * (1.f / E_DIM) - mu * mu + 1e-5f);
#pragma unroll
    for (int i = 0; i < 3; ++i) {
        int c = lane * 4 + i * 256;
        float4 gg = *(const float4*)(g + c);
        float4 bb = *(const float4*)(b + c);
        float4 o;
        o.x = (v[i].x - mu) * rstd * gg.x + bb.x;
        o.y = (v[i].y - mu) * rstd * gg.y + bb.y;
        o.z = (v[i].z - mu) * rstd * gg.z + bb.z;
        o.w = (v[i].w - mu) * rstd * gg.w + bb.w;
        ushortx4 o4;
        o4[0] = f2bf(o.x); o4[1] = f2bf(o.y); o4[2] = f2bf(o.z); o4[3] = f2bf(o.w);
        *(ushortx4*)(out + row * E_DIM + c) = o4;
        if (i == 0 && lane < 2) {
            float4 r4 = *(const float4*)(ry + lane * 4);
            float* qo = qout + row * NQ + lane * 4;
            qo[0] = __cosf(o.x) * __cosf(r4.x);
            qo[1] = __cosf(o.y) * __cosf(r4.y);
            qo[2] = __cosf(o.z) * __cosf(r4.z);
            qo[3] = __cosf(o.w) * __cosf(r4.w);
        }
    }
}

// ---------------------------------------------------------------------------
// Kernel 6: LN2: out(f32) = LN(x1_bf16 + ffn_bf16)
// ---------------------------------------------------------------------------
__global__ __launch_bounds__(256) void k_ln2(const ushort* __restrict__ x,
                                             const ushort* __restrict__ y,
                                             const float* __restrict__ g,
                                             const float* __restrict__ b,
                                             float* __restrict__ out) {
    const int lane = threadIdx.x & 63;
    const int wave = threadIdx.x >> 6;
    const long row = (long)blockIdx.x * 4 + wave;
    const ushort* xr = x + row * E_DIM;
    const ushort* yr = y + row * E_DIM;
    float4 v[3];
    float s = 0.f, ss = 0.f;
#pragma unroll
    for (int i = 0; i < 3; ++i) {
        int c = lane * 4 + i * 256;
        ushortx4 a4 = *(const ushortx4*)(xr + c);
        ushortx4 d4 = *(const ushortx4*)(yr + c);
        v[i].x = bf2f(a4[0]) + bf2f(d4[0]); v[i].y = bf2f(a4[1]) + bf2f(d4[1]);
        v[i].z = bf2f(a4[2]) + bf2f(d4[2]); v[i].w = bf2f(a4[3]) + bf2f(d4[3]);
        s  += v[i].x + v[i].y + v[i].z + v[i].w;
        ss += v[i].x * v[i].x + v[i].y * v[i].y + v[i].z * v[i].z + v[i].w * v[i].w;
    }
#pragma unroll
    for (int o = 1; o < 64; o <<= 1) {
        s  += __shfl_xor(s, o);
        ss += __shfl_xor(ss, o);
    }
    const float mu = s * (1.f / E_DIM);
    const float rstd = rsqrtf(ss * (1.f / E_DIM) - mu * mu + 1e-5f);
#pragma unroll
    for (int i = 0; i < 3; ++i) {
        int c = lane * 4 + i * 256;
        float4 gg = *(const float4*)(g + c);
        float4 bb = *(const float4*)(b + c);
        float4 o;
        o.x = (v[i].x - mu) * rstd * gg.x + bb.x;
        o.y = (v[i].y - mu) * rstd * gg.y + bb.y;
        o.z = (v[i].z - mu) * rstd * gg.z + bb.z;
        o.w = (v[i].w - mu) * rstd * gg.w + bb.w;
        *(float4*)(out + row * E_DIM + c) = o;
    }
}

// ---------------------------------------------------------------------------

extern "C" void kernel_launch(void* const* d_in, const int* in_sizes, int n_in,
                              void* d_out, int out_size, void* d_ws, size_t ws_size,
                              hipStream_t stream) {
    const float* x   = (const float*)d_in[0];
    const float* rx  = (const float*)d_in[1];
    const float* ry  = (const float*)d_in[2];
    const float* Wc  = (const float*)d_in[3];
    const float* bc  = (const float*)d_in[4];
    const float* W1  = (const float*)d_in[5];
    const float* b1  = (const float*)d_in[6];
    const float* W2  = (const float*)d_in[7];
    const float* b2  = (const float*)d_in[8];
    const float* g1  = (const float*)d_in[9];
    const float* be1 = (const float*)d_in[10];
    const float* g2  = (const float*)d_in[11];
    const float* be2 = (const float*)d_in[12];
    float* out = (float*)d_out;

    char* ws = (char*)d_ws;
    ushort* wcT  = (ushort*)ws;                 ws += (size_t)E_DIM * E_DIM * 2;      // 1.2 MB
    ushort* attn = (ushort*)ws;                 ws += (size_t)M_ROWS * E_DIM * 2;     // 25 MB (bf16, reused as ffn_out)
    ushort* x1   = (ushort*)ws;                 ws += (size_t)M_ROWS * E_DIM * 2;     // 25 MB (bf16)
    float*  q    = (float*)ws;                  ws += (size_t)M_ROWS * NQ * 4;        // 0.5 MB
    uchar*  w2T8 = (uchar*)ws;                  ws += (size_t)E_DIM * FFN_DIM;        // 2.4 MB (tiled)
    ushort* w1tb = (ushort*)ws;                 ws += (size_t)FFN_DIM * NQ * 2;       // 48 KB

    // 1. WcT = bf16(Wc^T);  W2T8 = fp8(W2^T * 32) tiled;  w1tb = bf16(W1^T)
    k_transpose_bf<<<dim3(E_DIM / 32, E_DIM / 32), 256, 0, stream>>>(Wc, wcT, E_DIM, E_DIM);
    k_transpose_fp8t<<<dim3(E_DIM / 32, FFN_DIM / 32), 256, 0, stream>>>(W2, w2T8, FFN_DIM, E_DIM);
    k_w1t<<<dim3(FFN_DIM / 256), 256, 0, stream>>>(W1, w1tb);
    // 2. attn(bf16) = cos(x+rx) @ Wc + bc   (cos fused into staging)
    k_gemm1<<<dim3(M_ROWS / 128, E_DIM / 128), 256, 0, stream>>>(x, wcT, rx, bc, attn, M_ROWS, E_DIM, E_DIM);
    // 3. x1(bf16) = LN(x + attn); q = cos(x1[:, :8]) * cos(ry)
    k_ln1<<<M_ROWS / 4, 256, 0, stream>>>(x, attn, g1, be1, x1, q, ry);
    // 4+5 fused. ffn(bf16) = (relu(q@W1+b1)*16 @ w2T8)/512 + b2  (reuse attn)
    k_ffn_fused<<<dim3(M_ROWS / 64, E_DIM / 192), 256, 0, stream>>>(q, w1tb, b1, w2T8, b2, attn);
    // 6. out = LN(x1 + ffn)
    k_ln2<<<M_ROWS / 4, 256, 0, stream>>>(x1, attn, g2, be2, out);
}

// Round 11
// 253.653 us; speedup vs baseline: 1.1702x; 1.0901x over previous
//
#include <hip/hip_runtime.h>
#include <hip/hip_fp8.h>
#include <math.h>

#define M_ROWS 16384   // B*S
#define E_DIM 768
#define FFN_DIM 3072
#define NQ 8

// h stored as fp8*16, W2^T as fp8*32; GEMM3 epilogue multiplies by 1/512.
#define HSCALE 16.0f
#define WSCALE 32.0f
#define INV_SCALE (1.0f / (16.0f * 32.0f))

typedef __bf16 bf16x8 __attribute__((ext_vector_type(8)));
typedef float f32x4 __attribute__((ext_vector_type(4)));
typedef unsigned short ushortx8 __attribute__((ext_vector_type(8)));
typedef unsigned short ushortx4 __attribute__((ext_vector_type(4)));
typedef int intx4 __attribute__((ext_vector_type(4)));
typedef int intx8 __attribute__((ext_vector_type(8)));
typedef unsigned short ushort;
typedef unsigned char uchar;

union F8frag { intx4 h[2]; intx8 v; };

static __device__ __forceinline__ ushort f2bf(float f) {
    unsigned u = __float_as_uint(f);
    unsigned r = (u + 0x7FFFu + ((u >> 16) & 1u)) >> 16;
    return (ushort)r;
}
static __device__ __forceinline__ float bf2f(ushort u) {
    return __uint_as_float(((unsigned)u) << 16);
}
static __device__ __forceinline__ uchar f2fp8(float f) {
    return (uchar)__hip_cvt_float_to_fp8(f, __HIP_SATFINITE, __HIP_E4M3);
}
static __device__ __forceinline__ bf16x8 as_bf16x8(ushortx8 v) {
    union { ushortx8 u; bf16x8 b; } x; x.u = v; return x.b;
}
// async global->LDS, 16B per lane; LDS dest = wave-uniform base + lane*16
static __device__ __forceinline__ void gload_lds16(const void* g, void* l) {
    __builtin_amdgcn_global_load_lds(
        (const __attribute__((address_space(1))) unsigned*)g,
        (__attribute__((address_space(3))) unsigned*)l, 16, 0, 0);
}

// Tiled fp8 layout (h8, w2T8): value (r, k) at
//   base + ((r>>4)*(K/16) + (k>>4))*256 + (r&15)*16 + (k&15)

// ---------------------------------------------------------------------------
// Kernel 0: cosA = bf16(cos(x + rx)) elementwise.  (R7-verified)
// ---------------------------------------------------------------------------
__global__ __launch_bounds__(256) void k_cosA(const float* __restrict__ x,
                                              const float* __restrict__ rx,
                                              ushort* __restrict__ out) {
    const long i = ((long)blockIdx.x * 256 + threadIdx.x) * 8;
    float4 lo = *(const float4*)(x + i);
    float4 hi = *(const float4*)(x + i + 4);
    const float* rxp = rx + (i & 63);
    float4 rlo = *(const float4*)(rxp);
    float4 rhi = *(const float4*)(rxp + 4);
    ushortx8 o;
    o[0] = f2bf(__cosf(lo.x + rlo.x));
    o[1] = f2bf(__cosf(lo.y + rlo.y));
    o[2] = f2bf(__cosf(lo.z + rlo.z));
    o[3] = f2bf(__cosf(lo.w + rlo.w));
    o[4] = f2bf(__cosf(hi.x + rhi.x));
    o[5] = f2bf(__cosf(hi.y + rhi.y));
    o[6] = f2bf(__cosf(hi.z + rhi.z));
    o[7] = f2bf(__cosf(hi.w + rhi.w));
    *(ushortx8*)(out + i) = o;
}

// ---------------------------------------------------------------------------
// Kernel 1: transpose fp32 (R x C) -> bf16 (C x R)   [for Wc]
// ---------------------------------------------------------------------------
__global__ __launch_bounds__(256) void k_transpose_bf(const float* __restrict__ in,
                                                      ushort* __restrict__ out,
                                                      int R, int C) {
    __shared__ float tile[32][33];
    int c0 = blockIdx.x * 32, r0 = blockIdx.y * 32;
    int tx = threadIdx.x & 31, ty = threadIdx.x >> 5;
#pragma unroll
    for (int i = 0; i < 32; i += 8)
        tile[ty + i][tx] = in[(long)(r0 + ty + i) * C + c0 + tx];
    __syncthreads();
#pragma unroll
    for (int i = 0; i < 32; i += 8)
        out[(long)(c0 + ty + i) * R + r0 + tx] = f2bf(tile[tx][ty + i]);
}

// ---------------------------------------------------------------------------
// Kernel 2: W2 [R=K][C=N] f32 -> w2T8 fp8*WSCALE in TILED [N][K] layout.
// ---------------------------------------------------------------------------
__global__ __launch_bounds__(256) void k_transpose_fp8t(const float* __restrict__ in,
                                                        uchar* __restrict__ out,
                                                        int R, int C) {
    __shared__ float tile[32][33];
    int c0 = blockIdx.x * 32, r0 = blockIdx.y * 32;
    int tx = threadIdx.x & 31, ty = threadIdx.x >> 5;
#pragma unroll
    for (int i = 0; i < 32; i += 8)
        tile[ty + i][tx] = in[(long)(r0 + ty + i) * C + c0 + tx];
    __syncthreads();
    int k = r0 + tx;
#pragma unroll
    for (int i = 0; i < 32; i += 8) {
        int n = c0 + ty + i;
        long addr = ((long)(n >> 4) * (R >> 4) + (k >> 4)) * 256 + (n & 15) * 16 + (k & 15);
        out[addr] = f2fp8(tile[tx][ty + i] * WSCALE);
    }
}

// ---------------------------------------------------------------------------
// Kernel 2b: W1 [NQ][FFN] f32 -> w1t [FFN][NQ] bf16 (16B row per n).
// ---------------------------------------------------------------------------
__global__ __launch_bounds__(256) void k_w1t(const float* __restrict__ W1,
                                             ushort* __restrict__ w1t) {
    int n = blockIdx.x * 256 + threadIdx.x;
    ushortx8 o;
#pragma unroll
    for (int j = 0; j < NQ; ++j) o[j] = f2bf(W1[j * FFN_DIM + n]);
    *(ushortx8*)(w1t + (long)n * NQ) = o;
}

// ---------------------------------------------------------------------------
// Kernel 3: GEMM1: C[M,N] = cosA[M,K] * Bt[N,K]^T + bias[N], bf16 out.
// gload_lds width=16 staging (R7-verified addresses: linear LDS dest,
// source chunk (tid&7)^(srow&7) so slot p of row r holds chunk p^(r&7));
// single 32KB buffer, 2-barrier loop (R4/R6-verified sync structure).
// Read side identical to R6.
// ---------------------------------------------------------------------------
__global__ __launch_bounds__(256, 2)
void k_gemm1(const ushort* __restrict__ A, const ushort* __restrict__ Bt,
             const float* __restrict__ bias, ushort* __restrict__ C,
             int M, int N, int K) {
    __shared__ __align__(16) ushort lsA[128 * 64];
    __shared__ __align__(16) ushort lsB[128 * 64];
    const int tid = threadIdx.x;
    const int lane = tid & 63;
    const int wave = tid >> 6;
    const int wm = wave & 1, wn = wave >> 1;
    const long m0 = (long)blockIdx.x * 128;
    const long n0 = (long)blockIdx.y * 128;

    const int srow = tid >> 3;                     // 0..31
    const int schunk = (tid & 7) ^ (srow & 7);     // source chunk for this slot
    const ushort* gA = A + (m0 + srow) * (long)K + schunk * 8;
    const ushort* gB = Bt + (n0 + srow) * (long)K + schunk * 8;

    f32x4 acc[4][4] = {};
    const int rbase = lane & 15;
    const int khalf = lane >> 4;
    const int rswz = lane & 7;

    for (int kt = 0; kt < K; kt += 64) {
        if (kt) __syncthreads();      // all waves done reading previous tile
#pragma unroll
        for (int i = 0; i < 4; ++i) {
            gload_lds16(gA + kt + (long)(32 * i) * K, lsA + i * 2048 + wave * 512);
            gload_lds16(gB + kt + (long)(32 * i) * K, lsB + i * 2048 + wave * 512);
        }
        __syncthreads();              // drains DMA (vmcnt(0) before barrier)
#pragma unroll
        for (int kk = 0; kk < 64; kk += 32) {
            const int ko = (((kk >> 3) + khalf) ^ rswz) * 8;
            bf16x8 af[4], bfr[4];
#pragma unroll
            for (int t = 0; t < 4; ++t) {
                af[t]  = as_bf16x8(*(const ushortx8*)&lsA[(wm * 64 + t * 16 + rbase) * 64 + ko]);
                bfr[t] = as_bf16x8(*(const ushortx8*)&lsB[(wn * 64 + t * 16 + rbase) * 64 + ko]);
            }
#pragma unroll
            for (int tm = 0; tm < 4; ++tm)
#pragma unroll
                for (int tn = 0; tn < 4; ++tn)
                    acc[tm][tn] = __builtin_amdgcn_mfma_f32_16x16x32_bf16(af[tm], bfr[tn], acc[tm][tn], 0, 0, 0);
        }
    }

    const int cr = (lane >> 4) * 4;
    const int cc = lane & 15;
#pragma unroll
    for (int tm = 0; tm < 4; ++tm)
#pragma unroll
        for (int tn = 0; tn < 4; ++tn) {
            long col = n0 + wn * 64 + tn * 16 + cc;
            float bb = bias[col];
#pragma unroll
            for (int j = 0; j < 4; ++j) {
                long row = m0 + wm * 64 + tm * 16 + cr + j;
                C[row * N + col] = f2bf(acc[tm][tn][j] + bb);
            }
        }
}

// ---------------------------------------------------------------------------
// Kernel 4: MX-fp8 GEMM3.  A (tiled h8) staged via linear-copy DMA (R6);
// B (w2T8, 2.4MB, L2/L3-resident) read DIRECTLY from global with the tiled
// fragment pattern the fused kernel refcheck'd (R8/R9): per lane 2x16B at
//   (gtile*(K/16) + kt16)*256 + (n&15)*16,  16 lanes share each 256B block.
// Halves LDS traffic (the R6 kernel's measured bottleneck).
// ---------------------------------------------------------------------------
__global__ __launch_bounds__(256, 2)
void k_gemm_fp8(const uchar* __restrict__ A, const uchar* __restrict__ Bt,
                const float* __restrict__ bias, ushort* __restrict__ C,
                int M, int N, int K) {
    __shared__ __align__(16) uchar lsA[128 * 128];
    const int tid = threadIdx.x;
    const int lane = tid & 63;
    const int wave = tid >> 6;
    const int wm = wave & 1, wn = wave >> 1;
    const long m0 = (long)blockIdx.x * 128;
    const long n0 = (long)blockIdx.y * 128;

    const int shalf = tid >> 7;        // 0..1
    const int inner = tid & 127;
    const long grpStride = (long)K << 4;          // 16 rows * K bytes
    const uchar* gA = A + ((m0 >> 4) + shalf) * grpStride + inner * 16;
    const long iStep = grpStride * 2;             // +2 groups per i
    const int K16 = K >> 4;

    f32x4 acc[4][4] = {};
    const int rbase = lane & 15;
    const int khalf = lane >> 4;   // 0..3

    int offA[4][2];
    const uchar* gBf[4];
#pragma unroll
    for (int f = 0; f < 4; ++f) {
        offA[f][0] = (wm * 4 + f) * 2048 + (((khalf << 1)    ) << 8) + rbase * 16;
        offA[f][1] = (wm * 4 + f) * 2048 + (((khalf << 1) | 1) << 8) + rbase * 16;
        gBf[f] = Bt + ((long)((n0 >> 4) + wn * 4 + f) * K16 + khalf * 2) * 256 + rbase * 16;
    }

    for (int kt = 0; kt < K; kt += 128) {
        if (kt) __syncthreads();      // all waves done reading previous A-tile
        const long ko = (long)(kt >> 4) * 256;
#pragma unroll
        for (int i = 0; i < 4; ++i)
            gload_lds16(gA + ko + i * iStep, lsA + i * 4096 + wave * 1024);
        __syncthreads();              // drains DMA

        F8frag la[4], lb[4];
#pragma unroll
        for (int f = 0; f < 4; ++f) {
            la[f].h[0] = *(const intx4*)&lsA[offA[f][0]];
            la[f].h[1] = *(const intx4*)&lsA[offA[f][1]];
            lb[f].h[0] = *(const intx4*)(gBf[f] + ko);
            lb[f].h[1] = *(const intx4*)(gBf[f] + ko + 256);
        }
#pragma unroll
        for (int tm = 0; tm < 4; ++tm)
#pragma unroll
            for (int tn = 0; tn < 4; ++tn)
                acc[tm][tn] = __builtin_amdgcn_mfma_scale_f32_16x16x128_f8f6f4(
                    la[tm].v, lb[tn].v, acc[tm][tn],
                    0 /*A fmt: fp8 e4m3*/, 0 /*B fmt: fp8 e4m3*/,
                    0, 127 /*scaleA = 2^0*/, 0, 127 /*scaleB = 2^0*/);
    }

    const int cr = (lane >> 4) * 4;
    const int cc = lane & 15;
#pragma unroll
    for (int tm = 0; tm < 4; ++tm)
#pragma unroll
        for (int tn = 0; tn < 4; ++tn) {
            long col = n0 + wn * 64 + tn * 16 + cc;
            float bb = bias[col];
#pragma unroll
            for (int j = 0; j < 4; ++j) {
                long row = m0 + wm * 64 + tm * 16 + cr + j;
                C[row * N + col] = f2bf(acc[tm][tn][j] * INV_SCALE + bb);
            }
        }
}

// ---------------------------------------------------------------------------
// Kernel 5: LN1: x1(bf16) = LN(x_f32 + attn_bf16); q = cos(x1[:, :8])*cos(ry)
// ---------------------------------------------------------------------------
__global__ __launch_bounds__(256) void k_ln1(const float* __restrict__ x,
                                             const ushort* __restrict__ y,
                                             const float* __restrict__ g,
                                             const float* __restrict__ b,
                                             ushort* __restrict__ out,
                                             float* __restrict__ qout,
                                             const float* __restrict__ ry) {
    const int lane = threadIdx.x & 63;
    const int wave = threadIdx.x >> 6;
    const long row = (long)blockIdx.x * 4 + wave;
    const float* xr = x + row * E_DIM;
    const ushort* yr = y + row * E_DIM;
    float4 v[3];
    float s = 0.f, ss = 0.f;
#pragma unroll
    for (int i = 0; i < 3; ++i) {
        int c = lane * 4 + i * 256;
        float4 a = *(const float4*)(xr + c);
        ushortx4 d4 = *(const ushortx4*)(yr + c);
        v[i].x = a.x + bf2f(d4[0]); v[i].y = a.y + bf2f(d4[1]);
        v[i].z = a.z + bf2f(d4[2]); v[i].w = a.w + bf2f(d4[3]);
        s  += v[i].x + v[i].y + v[i].z + v[i].w;
        ss += v[i].x * v[i].x + v[i].y * v[i].y + v[i].z * v[i].z + v[i].w * v[i].w;
    }
#pragma unroll
    for (int o = 1; o < 64; o <<= 1) {
        s  += __shfl_xor(s, o);
        ss += __shfl_xor(ss, o);
    }
    const float mu = s * (1.f / E_DIM);
    const float rstd = rsqrtf(ss * (1.f / E_DIM) - mu * mu + 1e-5f);
#pragma unroll
    for (int i = 0; i < 3; ++i) {
        int c = lane * 4 + i * 256;
        float4 gg = *(const float4*)(g + c);
        float4 bb = *(const float4*)(b + c);
        float4 o;
        o.x = (v[i].x - mu) * rstd * gg.x + bb.x;
        o.y = (v[i].y - mu) * rstd * gg.y + bb.y;
        o.z = (v[i].z - mu) * rstd * gg.z + bb.z;
        o.w = (v[i].w - mu) * rstd * gg.w + bb.w;
        ushortx4 o4;
        o4[0] = f2bf(o.x); o4[1] = f2bf(o.y); o4[2] = f2bf(o.z); o4[3] = f2bf(o.w);
        *(ushortx4*)(out + row * E_DIM + c) = o4;
        if (i == 0 && lane < 2) {
            float4 r4 = *(const float4*)(ry + lane * 4);
            float* qo = qout + row * NQ + lane * 4;
            qo[0] = __cosf(o.x) * __cosf(r4.x);
            qo[1] = __cosf(o.y) * __cosf(r4.y);
            qo[2] = __cosf(o.z) * __cosf(r4.z);
            qo[3] = __cosf(o.w) * __cosf(r4.w);
        }
    }
}

// ---------------------------------------------------------------------------
// Kernel 6: LN2: out(f32) = LN(x1_bf16 + ffn_bf16)
// ---------------------------------------------------------------------------
__global__ __launch_bounds__(256) void k_ln2(const ushort* __restrict__ x,
                                             const ushort* __restrict__ y,
                                             const float* __restrict__ g,
                                             const float* __restrict__ b,
                                             float* __restrict__ out) {
    const int lane = threadIdx.x & 63;
    const int wave = threadIdx.x >> 6;
    const long row = (long)blockIdx.x * 4 + wave;
    const ushort* xr = x + row * E_DIM;
    const ushort* yr = y + row * E_DIM;
    float4 v[3];
    float s = 0.f, ss = 0.f;
#pragma unroll
    for (int i = 0; i < 3; ++i) {
        int c = lane * 4 + i * 256;
        ushortx4 a4 = *(const ushortx4*)(xr + c);
        ushortx4 d4 = *(const ushortx4*)(yr + c);
        v[i].x = bf2f(a4[0]) + bf2f(d4[0]); v[i].y = bf2f(a4[1]) + bf2f(d4[1]);
        v[i].z = bf2f(a4[2]) + bf2f(d4[2]); v[i].w = bf2f(a4[3]) + bf2f(d4[3]);
        s  += v[i].x + v[i].y + v[i].z + v[i].w;
        ss += v[i].x * v[i].x + v[i].y * v[i].y + v[i].z * v[i].z + v[i].w * v[i].w;
    }
#pragma unroll
    for (int o = 1; o < 64; o <<= 1) {
        s  += __shfl_xor(s, o);
        ss += __shfl_xor(ss, o);
    }
    const float mu = s * (1.f / E_DIM);
    const float rstd = rsqrtf(ss * (1.f / E_DIM) - mu * mu + 1e-5f);
#pragma unroll
    for (int i = 0; i < 3; ++i) {
        int c = lane * 4 + i * 256;
        float4 gg = *(const float4*)(g + c);
        float4 bb = *(const float4*)(b + c);
        float4 o;
        o.x = (v[i].x - mu) * rstd * gg.x + bb.x;
        o.y = (v[i].y - mu) * rstd * gg.y + bb.y;
        o.z = (v[i].z - mu) * rstd * gg.z + bb.z;
        o.w = (v[i].w - mu) * rstd * gg.w + bb.w;
        *(float4*)(out + row * E_DIM + c) = o;
    }
}

// ---------------------------------------------------------------------------
// Kernel 7: MFMA FFN1, TILED output (one contiguous 256B store per wave).
// (R6-verified)
// ---------------------------------------------------------------------------
__global__ __launch_bounds__(256) void k_ffn1(const float* __restrict__ q,
                                              const ushort* __restrict__ w1t,
                                              const float* __restrict__ b1,
                                              uchar* __restrict__ h) {
    const int lane = threadIdx.x & 63;
    const int wv = threadIdx.x >> 6;
    const int half = lane >> 4;       // 0..3
    const int lid = lane & 15;
    const long mrow = (long)blockIdx.x * 64 + wv * 16 + lid;
    const int n0 = blockIdx.y * 768;
    const long mtile = (long)blockIdx.x * 4 + wv;   // mrow >> 4

    bf16x8 qf = {};
    if (lane < 16) {
        float4 lo = *(const float4*)(q + mrow * NQ);
        float4 hi = *(const float4*)(q + mrow * NQ + 4);
        ushortx8 u;
        u[0] = f2bf(lo.x); u[1] = f2bf(lo.y); u[2] = f2bf(lo.z); u[3] = f2bf(lo.w);
        u[4] = f2bf(hi.x); u[5] = f2bf(hi.y); u[6] = f2bf(hi.z); u[7] = f2bf(hi.w);
        qf = as_bf16x8(u);
    }
    uchar* htile = h + mtile * (FFN_DIM / 16) * 256 + lid * 16 + half * 4;

#pragma unroll 4
    for (int nt = 0; nt < 48; ++nt) {
        const int nb = n0 + nt * 16;
        bf16x8 wf = {};
        if (lane < 16) wf = as_bf16x8(*(const ushortx8*)(w1t + (long)(nb + lid) * NQ));
        f32x4 acc = {};
        acc = __builtin_amdgcn_mfma_f32_16x16x32_bf16(wf, qf, acc, 0, 0, 0);
        float4 bb = *(const float4*)(b1 + nb + half * 4);
        uchar4 o;
        o.x = f2fp8(fmaxf(acc[0] + bb.x, 0.f) * HSCALE);
        o.y = f2fp8(fmaxf(acc[1] + bb.y, 0.f) * HSCALE);
        o.z = f2fp8(fmaxf(acc[2] + bb.z, 0.f) * HSCALE);
        o.w = f2fp8(fmaxf(acc[3] + bb.w, 0.f) * HSCALE);
        *(uchar4*)(htile + (long)(nb >> 4) * 256) = o;
    }
}

// ---------------------------------------------------------------------------

extern "C" void kernel_launch(void* const* d_in, const int* in_sizes, int n_in,
                              void* d_out, int out_size, void* d_ws, size_t ws_size,
                              hipStream_t stream) {
    const float* x   = (const float*)d_in[0];
    const float* rx  = (const float*)d_in[1];
    const float* ry  = (const float*)d_in[2];
    const float* Wc  = (const float*)d_in[3];
    const float* bc  = (const float*)d_in[4];
    const float* W1  = (const float*)d_in[5];
    const float* b1  = (const float*)d_in[6];
    const float* W2  = (const float*)d_in[7];
    const float* b2  = (const float*)d_in[8];
    const float* g1  = (const float*)d_in[9];
    const float* be1 = (const float*)d_in[10];
    const float* g2  = (const float*)d_in[11];
    const float* be2 = (const float*)d_in[12];
    float* out = (float*)d_out;

    char* ws = (char*)d_ws;
    ushort* wcT  = (ushort*)ws;                 ws += (size_t)E_DIM * E_DIM * 2;      // 1.2 MB
    ushort* attn = (ushort*)ws;                 ws += (size_t)M_ROWS * E_DIM * 2;     // 25 MB (bf16, reused as ffn_out)
    ushort* x1   = (ushort*)ws;                 ws += (size_t)M_ROWS * E_DIM * 2;     // 25 MB (bf16)
    float*  q    = (float*)ws;                  ws += (size_t)M_ROWS * NQ * 4;        // 0.5 MB
    uchar*  w2T8 = (uchar*)ws;                  ws += (size_t)E_DIM * FFN_DIM;        // 2.4 MB (tiled)
    uchar*  h8   = (uchar*)ws;                  ws += (size_t)M_ROWS * FFN_DIM;       // 50 MB (tiled)
    ushort* w1tb = (ushort*)ws;                 ws += (size_t)FFN_DIM * NQ * 2;       // 48 KB
    ushort* cosA = (ushort*)ws;                 ws += (size_t)M_ROWS * E_DIM * 2;     // 25 MB (bf16)

    // 1. cosA = bf16(cos(x+rx));  WcT = bf16(Wc^T);  W2T8 tiled;  w1tb
    k_cosA<<<dim3(M_ROWS * E_DIM / (256 * 8)), 256, 0, stream>>>(x, rx, cosA);
    k_transpose_bf<<<dim3(E_DIM / 32, E_DIM / 32), 256, 0, stream>>>(Wc, wcT, E_DIM, E_DIM);
    k_transpose_fp8t<<<dim3(E_DIM / 32, FFN_DIM / 32), 256, 0, stream>>>(W2, w2T8, FFN_DIM, E_DIM);
    k_w1t<<<dim3(FFN_DIM / 256), 256, 0, stream>>>(W1, w1tb);
    // 2. attn(bf16) = cosA @ Wc + bc   (gload_lds GEMM)
    k_gemm1<<<dim3(M_ROWS / 128, E_DIM / 128), 256, 0, stream>>>(cosA, wcT, bc, attn, M_ROWS, E_DIM, E_DIM);
    // 3. x1(bf16) = LN(x + attn); q = cos(x1[:, :8]) * cos(ry)
    k_ln1<<<M_ROWS / 4, 256, 0, stream>>>(x, attn, g1, be1, x1, q, ry);
    // 4. h8 = fp8(16 * relu(q @ W1 + b1))  (MFMA, tiled 256B-coalesced out)
    k_ffn1<<<dim3(M_ROWS / 64, FFN_DIM / 768), 256, 0, stream>>>(q, w1tb, b1, h8);
    // 5. ffn(bf16) = (h8 @ W2T8)/512 + b2  (A via DMA, B direct from L2)
    k_gemm_fp8<<<dim3(M_ROWS / 128, E_DIM / 128), 256, 0, stream>>>(h8, w2T8, b2, attn, M_ROWS, E_DIM, FFN_DIM);
    // 6. out = LN(x1 + ffn)
    k_ln2<<<M_ROWS / 4, 256, 0, stream>>>(x1, attn, g2, be2, out);
}

// Round 12
// 250.384 us; speedup vs baseline: 1.1855x; 1.0131x over previous
//
#include <hip/hip_runtime.h>
#include <hip/hip_fp8.h>
#include <math.h>

#define M_ROWS 16384   // B*S
#define E_DIM 768
#define FFN_DIM 3072
#define NQ 8

// h stored as fp8*16, W2^T as fp8*32; GEMM3 epilogue multiplies by 1/512.
#define HSCALE 16.0f
#define WSCALE 32.0f
#define INV_SCALE (1.0f / (16.0f * 32.0f))

typedef __bf16 bf16x8 __attribute__((ext_vector_type(8)));
typedef float f32x4 __attribute__((ext_vector_type(4)));
typedef unsigned short ushortx8 __attribute__((ext_vector_type(8)));
typedef unsigned short ushortx4 __attribute__((ext_vector_type(4)));
typedef int intx4 __attribute__((ext_vector_type(4)));
typedef int intx8 __attribute__((ext_vector_type(8)));
typedef unsigned short ushort;
typedef unsigned char uchar;

union F8frag { intx4 h[2]; intx8 v; };

static __device__ __forceinline__ ushort f2bf(float f) {
    unsigned u = __float_as_uint(f);
    unsigned r = (u + 0x7FFFu + ((u >> 16) & 1u)) >> 16;
    return (ushort)r;
}
static __device__ __forceinline__ float bf2f(ushort u) {
    return __uint_as_float(((unsigned)u) << 16);
}
static __device__ __forceinline__ uchar f2fp8(float f) {
    return (uchar)__hip_cvt_float_to_fp8(f, __HIP_SATFINITE, __HIP_E4M3);
}
static __device__ __forceinline__ bf16x8 as_bf16x8(ushortx8 v) {
    union { ushortx8 u; bf16x8 b; } x; x.u = v; return x.b;
}
// async global->LDS, 16B per lane; LDS dest = wave-uniform base + lane*16
static __device__ __forceinline__ void gload_lds16(const void* g, void* l) {
    __builtin_amdgcn_global_load_lds(
        (const __attribute__((address_space(1))) unsigned*)g,
        (__attribute__((address_space(3))) unsigned*)l, 16, 0, 0);
}

// Tiled fp8 layout (h8, w2T8): value (r, k) at
//   base + ((r>>4)*(K/16) + (k>>4))*256 + (r&15)*16 + (k&15)

// ---------------------------------------------------------------------------
// Kernel 0: cosA = bf16(cos(x + rx)) elementwise.  (R7/R11-verified)
// ---------------------------------------------------------------------------
__global__ __launch_bounds__(256) void k_cosA(const float* __restrict__ x,
                                              const float* __restrict__ rx,
                                              ushort* __restrict__ out) {
    const long i = ((long)blockIdx.x * 256 + threadIdx.x) * 8;
    float4 lo = *(const float4*)(x + i);
    float4 hi = *(const float4*)(x + i + 4);
    const float* rxp = rx + (i & 63);
    float4 rlo = *(const float4*)(rxp);
    float4 rhi = *(const float4*)(rxp + 4);
    ushortx8 o;
    o[0] = f2bf(__cosf(lo.x + rlo.x));
    o[1] = f2bf(__cosf(lo.y + rlo.y));
    o[2] = f2bf(__cosf(lo.z + rlo.z));
    o[3] = f2bf(__cosf(lo.w + rlo.w));
    o[4] = f2bf(__cosf(hi.x + rhi.x));
    o[5] = f2bf(__cosf(hi.y + rhi.y));
    o[6] = f2bf(__cosf(hi.z + rhi.z));
    o[7] = f2bf(__cosf(hi.w + rhi.w));
    *(ushortx8*)(out + i) = o;
}

// ---------------------------------------------------------------------------
// Kernel 1: transpose fp32 (R x C) -> bf16 (C x R)   [for Wc]
// ---------------------------------------------------------------------------
__global__ __launch_bounds__(256) void k_transpose_bf(const float* __restrict__ in,
                                                      ushort* __restrict__ out,
                                                      int R, int C) {
    __shared__ float tile[32][33];
    int c0 = blockIdx.x * 32, r0 = blockIdx.y * 32;
    int tx = threadIdx.x & 31, ty = threadIdx.x >> 5;
#pragma unroll
    for (int i = 0; i < 32; i += 8)
        tile[ty + i][tx] = in[(long)(r0 + ty + i) * C + c0 + tx];
    __syncthreads();
#pragma unroll
    for (int i = 0; i < 32; i += 8)
        out[(long)(c0 + ty + i) * R + r0 + tx] = f2bf(tile[tx][ty + i]);
}

// ---------------------------------------------------------------------------
// Kernel 2: W2 [R=K][C=N] f32 -> w2T8 fp8*WSCALE in TILED [N][K] layout.
// ---------------------------------------------------------------------------
__global__ __launch_bounds__(256) void k_transpose_fp8t(const float* __restrict__ in,
                                                        uchar* __restrict__ out,
                                                        int R, int C) {
    __shared__ float tile[32][33];
    int c0 = blockIdx.x * 32, r0 = blockIdx.y * 32;
    int tx = threadIdx.x & 31, ty = threadIdx.x >> 5;
#pragma unroll
    for (int i = 0; i < 32; i += 8)
        tile[ty + i][tx] = in[(long)(r0 + ty + i) * C + c0 + tx];
    __syncthreads();
    int k = r0 + tx;
#pragma unroll
    for (int i = 0; i < 32; i += 8) {
        int n = c0 + ty + i;
        long addr = ((long)(n >> 4) * (R >> 4) + (k >> 4)) * 256 + (n & 15) * 16 + (k & 15);
        out[addr] = f2fp8(tile[tx][ty + i] * WSCALE);
    }
}

// ---------------------------------------------------------------------------
// Kernel 2b: W1 [NQ][FFN] f32 -> w1t [FFN][NQ] bf16 (16B row per n).
// ---------------------------------------------------------------------------
__global__ __launch_bounds__(256) void k_w1t(const float* __restrict__ W1,
                                             ushort* __restrict__ w1t) {
    int n = blockIdx.x * 256 + threadIdx.x;
    ushortx8 o;
#pragma unroll
    for (int j = 0; j < NQ; ++j) o[j] = f2bf(W1[j * FFN_DIM + n]);
    *(ushortx8*)(w1t + (long)n * NQ) = o;
}

// ---------------------------------------------------------------------------
// Kernel 3: GEMM1: C[M,N] = cosA[M,K] * Bt[N,K]^T + bias[N], bf16 out.
// (R11-verified: gload_lds width=16 staging, linear LDS dest, source chunk
// (tid&7)^(srow&7); single 32KB buffer, 2-barrier loop.)
// ---------------------------------------------------------------------------
__global__ __launch_bounds__(256, 2)
void k_gemm1(const ushort* __restrict__ A, const ushort* __restrict__ Bt,
             const float* __restrict__ bias, ushort* __restrict__ C,
             int M, int N, int K) {
    __shared__ __align__(16) ushort lsA[128 * 64];
    __shared__ __align__(16) ushort lsB[128 * 64];
    const int tid = threadIdx.x;
    const int lane = tid & 63;
    const int wave = tid >> 6;
    const int wm = wave & 1, wn = wave >> 1;
    const long m0 = (long)blockIdx.x * 128;
    const long n0 = (long)blockIdx.y * 128;

    const int srow = tid >> 3;                     // 0..31
    const int schunk = (tid & 7) ^ (srow & 7);     // source chunk for this slot
    const ushort* gA = A + (m0 + srow) * (long)K + schunk * 8;
    const ushort* gB = Bt + (n0 + srow) * (long)K + schunk * 8;

    f32x4 acc[4][4] = {};
    const int rbase = lane & 15;
    const int khalf = lane >> 4;
    const int rswz = lane & 7;

    for (int kt = 0; kt < K; kt += 64) {
        if (kt) __syncthreads();      // all waves done reading previous tile
#pragma unroll
        for (int i = 0; i < 4; ++i) {
            gload_lds16(gA + kt + (long)(32 * i) * K, lsA + i * 2048 + wave * 512);
            gload_lds16(gB + kt + (long)(32 * i) * K, lsB + i * 2048 + wave * 512);
        }
        __syncthreads();              // drains DMA (vmcnt(0) before barrier)
#pragma unroll
        for (int kk = 0; kk < 64; kk += 32) {
            const int ko = (((kk >> 3) + khalf) ^ rswz) * 8;
            bf16x8 af[4], bfr[4];
#pragma unroll
            for (int t = 0; t < 4; ++t) {
                af[t]  = as_bf16x8(*(const ushortx8*)&lsA[(wm * 64 + t * 16 + rbase) * 64 + ko]);
                bfr[t] = as_bf16x8(*(const ushortx8*)&lsB[(wn * 64 + t * 16 + rbase) * 64 + ko]);
            }
#pragma unroll
            for (int tm = 0; tm < 4; ++tm)
#pragma unroll
                for (int tn = 0; tn < 4; ++tn)
                    acc[tm][tn] = __builtin_amdgcn_mfma_f32_16x16x32_bf16(af[tm], bfr[tn], acc[tm][tn], 0, 0, 0);
        }
    }

    const int cr = (lane >> 4) * 4;
    const int cc = lane & 15;
#pragma unroll
    for (int tm = 0; tm < 4; ++tm)
#pragma unroll
        for (int tn = 0; tn < 4; ++tn) {
            long col = n0 + wn * 64 + tn * 16 + cc;
            float bb = bias[col];
#pragma unroll
            for (int j = 0; j < 4; ++j) {
                long row = m0 + wm * 64 + tm * 16 + cr + j;
                C[row * N + col] = f2bf(acc[tm][tn][j] + bb);
            }
        }
}

// ---------------------------------------------------------------------------
// Kernel 4: MX-fp8 GEMM3 (R6/R7-verified, 40.6us): both operands TILED,
// staging is a LINEAR COPY via gload_lds (wave = 1KB contiguous global,
// linear LDS dest); LDS image [group][ktile][r&15][k&15]; lane fragment =
// 2 contiguous 16B chunks at (w*4+f)*2048 + (2*khalf|h)*256 + (lane&15)*16.
// 0 bank conflicts measured.  (B-direct-from-L2 variant regressed — R11.)
// ---------------------------------------------------------------------------
__global__ __launch_bounds__(256, 2)
void k_gemm_fp8(const uchar* __restrict__ A, const uchar* __restrict__ Bt,
                const float* __restrict__ bias, ushort* __restrict__ C,
                int M, int N, int K) {
    __shared__ __align__(16) uchar lsA[128 * 128];
    __shared__ __align__(16) uchar lsB[128 * 128];
    const int tid = threadIdx.x;
    const int lane = tid & 63;
    const int wave = tid >> 6;
    const int wm = wave & 1, wn = wave >> 1;
    const long m0 = (long)blockIdx.x * 128;
    const long n0 = (long)blockIdx.y * 128;

    const int shalf = tid >> 7;        // 0..1
    const int inner = tid & 127;
    const long grpStride = (long)K << 4;          // 16 rows * K bytes
    const uchar* gA = A + ((m0 >> 4) + shalf) * grpStride + inner * 16;
    const uchar* gB = Bt + ((n0 >> 4) + shalf) * grpStride + inner * 16;
    const long iStep = grpStride * 2;             // +2 groups per i

    f32x4 acc[4][4] = {};
    const int rbase = lane & 15;
    const int khalf = lane >> 4;   // 0..3

    int offA[4][2], offB[4][2];
#pragma unroll
    for (int f = 0; f < 4; ++f) {
#pragma unroll
        for (int h = 0; h < 2; ++h) {
            offA[f][h] = (wm * 4 + f) * 2048 + (((khalf << 1) | h) << 8) + rbase * 16;
            offB[f][h] = (wn * 4 + f) * 2048 + (((khalf << 1) | h) << 8) + rbase * 16;
        }
    }

    for (int kt = 0; kt < K; kt += 128) {
        if (kt) __syncthreads();
        const long ko = (long)(kt >> 4) * 256;
#pragma unroll
        for (int i = 0; i < 4; ++i) {
            gload_lds16(gA + ko + i * iStep, lsA + i * 4096 + wave * 1024);
            gload_lds16(gB + ko + i * iStep, lsB + i * 4096 + wave * 1024);
        }
        __syncthreads();

        F8frag la[4], lb[4];
#pragma unroll
        for (int f = 0; f < 4; ++f) {
            la[f].h[0] = *(const intx4*)&lsA[offA[f][0]];
            la[f].h[1] = *(const intx4*)&lsA[offA[f][1]];
            lb[f].h[0] = *(const intx4*)&lsB[offB[f][0]];
            lb[f].h[1] = *(const intx4*)&lsB[offB[f][1]];
        }
#pragma unroll
        for (int tm = 0; tm < 4; ++tm)
#pragma unroll
            for (int tn = 0; tn < 4; ++tn)
                acc[tm][tn] = __builtin_amdgcn_mfma_scale_f32_16x16x128_f8f6f4(
                    la[tm].v, lb[tn].v, acc[tm][tn],
                    0 /*A fmt: fp8 e4m3*/, 0 /*B fmt: fp8 e4m3*/,
                    0, 127 /*scaleA = 2^0*/, 0, 127 /*scaleB = 2^0*/);
    }

    const int cr = (lane >> 4) * 4;
    const int cc = lane & 15;
#pragma unroll
    for (int tm = 0; tm < 4; ++tm)
#pragma unroll
        for (int tn = 0; tn < 4; ++tn) {
            long col = n0 + wn * 64 + tn * 16 + cc;
            float bb = bias[col];
#pragma unroll
            for (int j = 0; j < 4; ++j) {
                long row = m0 + wm * 64 + tm * 16 + cr + j;
                C[row * N + col] = f2bf(acc[tm][tn][j] * INV_SCALE + bb);
            }
        }
}

// ---------------------------------------------------------------------------
// Kernel 5: LN1: x1(bf16) = LN(x_f32 + attn_bf16); q = cos(x1[:, :8])*cos(ry)
// ---------------------------------------------------------------------------
__global__ __launch_bounds__(256) void k_ln1(const float* __restrict__ x,
                                             const ushort* __restrict__ y,
                                             const float* __restrict__ g,
                                             const float* __restrict__ b,
                                             ushort* __restrict__ out,
                                             float* __restrict__ qout,
                                             const float* __restrict__ ry) {
    const int lane = threadIdx.x & 63;
    const int wave = threadIdx.x >> 6;
    const long row = (long)blockIdx.x * 4 + wave;
    const float* xr = x + row * E_DIM;
    const ushort* yr = y + row * E_DIM;
    float4 v[3];
    float s = 0.f, ss = 0.f;
#pragma unroll
    for (int i = 0; i < 3; ++i) {
        int c = lane * 4 + i * 256;
        float4 a = *(const float4*)(xr + c);
        ushortx4 d4 = *(const ushortx4*)(yr + c);
        v[i].x = a.x + bf2f(d4[0]); v[i].y = a.y + bf2f(d4[1]);
        v[i].z = a.z + bf2f(d4[2]); v[i].w = a.w + bf2f(d4[3]);
        s  += v[i].x + v[i].y + v[i].z + v[i].w;
        ss += v[i].x * v[i].x + v[i].y * v[i].y + v[i].z * v[i].z + v[i].w * v[i].w;
    }
#pragma unroll
    for (int o = 1; o < 64; o <<= 1) {
        s  += __shfl_xor(s, o);
        ss += __shfl_xor(ss, o);
    }
    const float mu = s * (1.f / E_DIM);
    const float rstd = rsqrtf(ss * (1.f / E_DIM) - mu * mu + 1e-5f);
#pragma unroll
    for (int i = 0; i < 3; ++i) {
        int c = lane * 4 + i * 256;
        float4 gg = *(const float4*)(g + c);
        float4 bb = *(const float4*)(b + c);
        float4 o;
        o.x = (v[i].x - mu) * rstd * gg.x + bb.x;
        o.y = (v[i].y - mu) * rstd * gg.y + bb.y;
        o.z = (v[i].z - mu) * rstd * gg.z + bb.z;
        o.w = (v[i].w - mu) * rstd * gg.w + bb.w;
        ushortx4 o4;
        o4[0] = f2bf(o.x); o4[1] = f2bf(o.y); o4[2] = f2bf(o.z); o4[3] = f2bf(o.w);
        *(ushortx4*)(out + row * E_DIM + c) = o4;
        if (i == 0 && lane < 2) {
            float4 r4 = *(const float4*)(ry + lane * 4);
            float* qo = qout + row * NQ + lane * 4;
            qo[0] = __cosf(o.x) * __cosf(r4.x);
            qo[1] = __cosf(o.y) * __cosf(r4.y);
            qo[2] = __cosf(o.z) * __cosf(r4.z);
            qo[3] = __cosf(o.w) * __cosf(r4.w);
        }
    }
}

// ---------------------------------------------------------------------------
// Kernel 6: LN2: out(f32) = LN(x1_bf16 + ffn_bf16)
// ---------------------------------------------------------------------------
__global__ __launch_bounds__(256) void k_ln2(const ushort* __restrict__ x,
                                             const ushort* __restrict__ y,
                                             const float* __restrict__ g,
                                             const float* __restrict__ b,
                                             float* __restrict__ out) {
    const int lane = threadIdx.x & 63;
    const int wave = threadIdx.x >> 6;
    const long row = (long)blockIdx.x * 4 + wave;
    const ushort* xr = x + row * E_DIM;
    const ushort* yr = y + row * E_DIM;
    float4 v[3];
    float s = 0.f, ss = 0.f;
#pragma unroll
    for (int i = 0; i < 3; ++i) {
        int c = lane * 4 + i * 256;
        ushortx4 a4 = *(const ushortx4*)(xr + c);
        ushortx4 d4 = *(const ushortx4*)(yr + c);
        v[i].x = bf2f(a4[0]) + bf2f(d4[0]); v[i].y = bf2f(a4[1]) + bf2f(d4[1]);
        v[i].z = bf2f(a4[2]) + bf2f(d4[2]); v[i].w = bf2f(a4[3]) + bf2f(d4[3]);
        s  += v[i].x + v[i].y + v[i].z + v[i].w;
        ss += v[i].x * v[i].x + v[i].y * v[i].y + v[i].z * v[i].z + v[i].w * v[i].w;
    }
#pragma unroll
    for (int o = 1; o < 64; o <<= 1) {
        s  += __shfl_xor(s, o);
        ss += __shfl_xor(ss, o);
    }
    const float mu = s * (1.f / E_DIM);
    const float rstd = rsqrtf(ss * (1.f / E_DIM) - mu * mu + 1e-5f);
#pragma unroll
    for (int i = 0; i < 3; ++i) {
        int c = lane * 4 + i * 256;
        float4 gg = *(const float4*)(g + c);
        float4 bb = *(const float4*)(b + c);
        float4 o;
        o.x = (v[i].x - mu) * rstd * gg.x + bb.x;
        o.y = (v[i].y - mu) * rstd * gg.y + bb.y;
        o.z = (v[i].z - mu) * rstd * gg.z + bb.z;
        o.w = (v[i].w - mu) * rstd * gg.w + bb.w;
        *(float4*)(out + row * E_DIM + c) = o;
    }
}

// ---------------------------------------------------------------------------
// Kernel 7: MFMA FFN1, TILED output (one contiguous 256B store per wave).
// (R6-verified)
// ---------------------------------------------------------------------------
__global__ __launch_bounds__(256) void k_ffn1(const float* __restrict__ q,
                                              const ushort* __restrict__ w1t,
                                              const float* __restrict__ b1,
                                              uchar* __restrict__ h) {
    const int lane = threadIdx.x & 63;
    const int wv = threadIdx.x >> 6;
    const int half = lane >> 4;       // 0..3
    const int lid = lane & 15;
    const long mrow = (long)blockIdx.x * 64 + wv * 16 + lid;
    const int n0 = blockIdx.y * 768;
    const long mtile = (long)blockIdx.x * 4 + wv;   // mrow >> 4

    bf16x8 qf = {};
    if (lane < 16) {
        float4 lo = *(const float4*)(q + mrow * NQ);
        float4 hi = *(const float4*)(q + mrow * NQ + 4);
        ushortx8 u;
        u[0] = f2bf(lo.x); u[1] = f2bf(lo.y); u[2] = f2bf(lo.z); u[3] = f2bf(lo.w);
        u[4] = f2bf(hi.x); u[5] = f2bf(hi.y); u[6] = f2bf(hi.z); u[7] = f2bf(hi.w);
        qf = as_bf16x8(u);
    }
    uchar* htile = h + mtile * (FFN_DIM / 16) * 256 + lid * 16 + half * 4;

#pragma unroll 4
    for (int nt = 0; nt < 48; ++nt) {
        const int nb = n0 + nt * 16;
        bf16x8 wf = {};
        if (lane < 16) wf = as_bf16x8(*(const ushortx8*)(w1t + (long)(nb + lid) * NQ));
        f32x4 acc = {};
        acc = __builtin_amdgcn_mfma_f32_16x16x32_bf16(wf, qf, acc, 0, 0, 0);
        float4 bb = *(const float4*)(b1 + nb + half * 4);
        uchar4 o;
        o.x = f2fp8(fmaxf(acc[0] + bb.x, 0.f) * HSCALE);
        o.y = f2fp8(fmaxf(acc[1] + bb.y, 0.f) * HSCALE);
        o.z = f2fp8(fmaxf(acc[2] + bb.z, 0.f) * HSCALE);
        o.w = f2fp8(fmaxf(acc[3] + bb.w, 0.f) * HSCALE);
        *(uchar4*)(htile + (long)(nb >> 4) * 256) = o;
    }
}

// ---------------------------------------------------------------------------

extern "C" void kernel_launch(void* const* d_in, const int* in_sizes, int n_in,
                              void* d_out, int out_size, void* d_ws, size_t ws_size,
                              hipStream_t stream) {
    const float* x   = (const float*)d_in[0];
    const float* rx  = (const float*)d_in[1];
    const float* ry  = (const float*)d_in[2];
    const float* Wc  = (const float*)d_in[3];
    const float* bc  = (const float*)d_in[4];
    const float* W1  = (const float*)d_in[5];
    const float* b1  = (const float*)d_in[6];
    const float* W2  = (const float*)d_in[7];
    const float* b2  = (const float*)d_in[8];
    const float* g1  = (const float*)d_in[9];
    const float* be1 = (const float*)d_in[10];
    const float* g2  = (const float*)d_in[11];
    const float* be2 = (const float*)d_in[12];
    float* out = (float*)d_out;

    char* ws = (char*)d_ws;
    ushort* wcT  = (ushort*)ws;                 ws += (size_t)E_DIM * E_DIM * 2;      // 1.2 MB
    ushort* attn = (ushort*)ws;                 ws += (size_t)M_ROWS * E_DIM * 2;     // 25 MB (bf16, reused as ffn_out)
    ushort* x1   = (ushort*)ws;                 ws += (size_t)M_ROWS * E_DIM * 2;     // 25 MB (bf16)
    float*  q    = (float*)ws;                  ws += (size_t)M_ROWS * NQ * 4;        // 0.5 MB
    uchar*  w2T8 = (uchar*)ws;                  ws += (size_t)E_DIM * FFN_DIM;        // 2.4 MB (tiled)
    uchar*  h8   = (uchar*)ws;                  ws += (size_t)M_ROWS * FFN_DIM;       // 50 MB (tiled)
    ushort* w1tb = (ushort*)ws;                 ws += (size_t)FFN_DIM * NQ * 2;       // 48 KB
    ushort* cosA = (ushort*)ws;                 ws += (size_t)M_ROWS * E_DIM * 2;     // 25 MB (bf16)

    // 1. cosA = bf16(cos(x+rx));  WcT = bf16(Wc^T);  W2T8 tiled;  w1tb
    k_cosA<<<dim3(M_ROWS * E_DIM / (256 * 8)), 256, 0, stream>>>(x, rx, cosA);
    k_transpose_bf<<<dim3(E_DIM / 32, E_DIM / 32), 256, 0, stream>>>(Wc, wcT, E_DIM, E_DIM);
    k_transpose_fp8t<<<dim3(E_DIM / 32, FFN_DIM / 32), 256, 0, stream>>>(W2, w2T8, FFN_DIM, E_DIM);
    k_w1t<<<dim3(FFN_DIM / 256), 256, 0, stream>>>(W1, w1tb);
    // 2. attn(bf16) = cosA @ Wc + bc   (gload_lds GEMM)
    k_gemm1<<<dim3(M_ROWS / 128, E_DIM / 128), 256, 0, stream>>>(cosA, wcT, bc, attn, M_ROWS, E_DIM, E_DIM);
    // 3. x1(bf16) = LN(x + attn); q = cos(x1[:, :8]) * cos(ry)
    k_ln1<<<M_ROWS / 4, 256, 0, stream>>>(x, attn, g1, be1, x1, q, ry);
    // 4. h8 = fp8(16 * relu(q @ W1 + b1))  (MFMA, tiled 256B-coalesced out)
    k_ffn1<<<dim3(M_ROWS / 64, FFN_DIM / 768), 256, 0, stream>>>(q, w1tb, b1, h8);
    // 5. ffn(bf16) = (h8 @ W2T8)/512 + b2  (both operands staged, linear DMA)
    k_gemm_fp8<<<dim3(M_ROWS / 128, E_DIM / 128), 256, 0, stream>>>(h8, w2T8, b2, attn, M_ROWS, E_DIM, FFN_DIM);
    // 6. out = LN(x1 + ffn)
    k_ln2<<<M_ROWS / 4, 256, 0, stream>>>(x1, attn, g2, be2, out);
}